// Round 2
// baseline (58312.073 us; speedup 1.0000x reference)
//
#include <hip/hip_runtime.h>
#include <hip/hip_bf16.h>

// Problem constants (from setup_inputs): B=32, D=128, T=2250, Q=32, K=1024
#define B_ 32
#define D_ 128
#define T_ 2250
#define Q_ 32
#define K_ 1024
#define N_ (B_ * T_)   // 72000

// ---------------------------------------------------------------------------
// Transpose embeddings [B, D, T] -> R32/R64 [N, D] with n = b*T + t
// ---------------------------------------------------------------------------
__global__ void transpose_kernel(const float* __restrict__ emb,
                                 float* __restrict__ R32,
                                 double* __restrict__ R64)
{
    __shared__ float tile[32][33];
    const int b  = blockIdx.z;
    const int t0 = blockIdx.x * 32;
    const int d0 = blockIdx.y * 32;

    for (int i = threadIdx.y; i < 32; i += 8) {
        int t = t0 + threadIdx.x;
        int d = d0 + i;
        tile[i][threadIdx.x] = (t < T_) ? emb[((size_t)b * D_ + d) * T_ + t] : 0.0f;
    }
    __syncthreads();
    for (int i = threadIdx.y; i < 32; i += 8) {
        int t = t0 + i;
        if (t < T_) {
            float v = tile[threadIdx.x][i];
            size_t o = ((size_t)b * T_ + t) * D_ + d0 + threadIdx.x;
            R32[o] = v;
            R64[o] = (double)v;
        }
    }
}

// ---------------------------------------------------------------------------
// Per-code squared norms: fp32 (fast pass) and fp64 (rescore). One wave/code.
// ---------------------------------------------------------------------------
__global__ __launch_bounds__(64) void norms_kernel(const float* __restrict__ codebooks,
                                                   float* __restrict__ normF,
                                                   double* __restrict__ normD)
{
    const int code = blockIdx.x;            // 0 .. Q*K-1
    const float* e = codebooks + (size_t)code * D_;
    const int lane = threadIdx.x;
    float f0 = e[lane];
    float f1 = e[lane + 64];
    double acc = (double)f0 * (double)f0 + (double)f1 * (double)f1;
    #pragma unroll
    for (int off = 32; off > 0; off >>= 1) acc += __shfl_down(acc, off);
    if (lane == 0) {
        normD[code] = acc;
        normF[code] = (float)acc;
    }
}

// ---------------------------------------------------------------------------
// Fast pass: each thread owns one point (fp32 row in 128 VGPRs), streams all
// K codes (wave-uniform -> scalar loads), tracks top-2. Near-ties flagged.
// ---------------------------------------------------------------------------
#define TAU 0.25f

__global__ __launch_bounds__(64) void layer_fast(
    const float* __restrict__ R32,
    const float* __restrict__ cb,      // [K, D] this layer's codebook
    const float* __restrict__ normF,   // [K]
    int* __restrict__ outIdx,          // [N]  (d_out + q*N)
    int* __restrict__ flagList,
    int* __restrict__ flagCount)
{
    __shared__ float lds[64 * 132];    // 64 rows, stride 132 floats (16B aligned)
    const int lane = threadIdx.x;
    const size_t rowBase = (size_t)blockIdx.x * 64;

    // Cooperative, coalesced staging of 64 r-rows (2048 float4) into LDS.
    const float4* Rv = (const float4*)(R32 + rowBase * D_);
    #pragma unroll
    for (int i = 0; i < 32; ++i) {
        int e = i * 64 + lane;
        int row = e >> 5, col = e & 31;
        float4 v = Rv[e];
        *(float4*)(&lds[row * 132 + col * 4]) = v;
    }
    __syncthreads();

    float r[128];
    #pragma unroll
    for (int j = 0; j < 32; ++j) {
        float4 v = *(const float4*)(&lds[lane * 132 + j * 4]);
        r[4 * j + 0] = v.x; r[4 * j + 1] = v.y;
        r[4 * j + 2] = v.z; r[4 * j + 3] = v.w;
    }

    float best1 = -3.4e38f, best2 = -3.4e38f;
    int bi = 0;
    for (int k = 0; k < K_; ++k) {
        const float* __restrict__ c = cb + (size_t)k * D_;  // wave-uniform address
        float a0 = 0.f, a1 = 0.f, a2 = 0.f, a3 = 0.f;
        #pragma unroll
        for (int j = 0; j < 32; ++j) {
            a0 = fmaf(r[4 * j + 0], c[4 * j + 0], a0);
            a1 = fmaf(r[4 * j + 1], c[4 * j + 1], a1);
            a2 = fmaf(r[4 * j + 2], c[4 * j + 2], a2);
            a3 = fmaf(r[4 * j + 3], c[4 * j + 3], a3);
        }
        float s = 2.0f * ((a0 + a1) + (a2 + a3)) - normF[k];
        if (s > best1)      { best2 = best1; best1 = s; bi = k; }  // strict > : first index wins
        else if (s > best2) { best2 = s; }
    }

    const int n = (int)rowBase + lane;
    outIdx[n] = bi;
    if (best1 - best2 < TAU) {
        int pos = atomicAdd(flagCount, 1);
        flagList[pos] = n;
    }
}

// ---------------------------------------------------------------------------
// fp64 rescore of flagged points against the fp64 residual. One wave/point.
// Tie-break: lower index wins (matches jnp.argmax first-occurrence).
// ---------------------------------------------------------------------------
__global__ __launch_bounds__(64) void layer_rescore(
    const double* __restrict__ R64,
    const float* __restrict__ cb,
    const double* __restrict__ normD,
    const int* __restrict__ flagList,
    const int* __restrict__ flagCount,
    int* __restrict__ outIdx)
{
    const int cnt = *flagCount;
    const int lane = threadIdx.x;
    for (int i = blockIdx.x; i < cnt; i += gridDim.x) {
        const int n = flagList[i];
        const double* __restrict__ r = R64 + (size_t)n * D_;  // wave-uniform
        double best = -1.0e300;
        int bi = K_;
        for (int k = lane; k < K_; k += 64) {
            const float* __restrict__ c = cb + (size_t)k * D_;
            double a0 = 0.0, a1 = 0.0;
            #pragma unroll 8
            for (int j = 0; j < D_; j += 2) {
                a0 = fma(r[j],     (double)c[j],     a0);
                a1 = fma(r[j + 1], (double)c[j + 1], a1);
            }
            double s = 2.0 * (a0 + a1) - normD[k];
            if (s > best) { best = s; bi = k; }   // strict > : lowest k in lane wins
        }
        #pragma unroll
        for (int off = 32; off > 0; off >>= 1) {
            double ob = __shfl_down(best, off);
            int    oi = __shfl_down(bi, off);
            if (ob > best || (ob == best && oi < bi)) { best = ob; bi = oi; }
        }
        if (lane == 0) outIdx[n] = bi;
    }
}

// ---------------------------------------------------------------------------
// Residual update in fp64: R64[n] -= cb[idx[n]]; R32 = (float)R64.
// One double2 (= 2 dims) per thread; N*64 threads.
// ---------------------------------------------------------------------------
__global__ void layer_update(double* __restrict__ R64,
                             float* __restrict__ R32,
                             const float* __restrict__ cb,
                             const int* __restrict__ outIdx)
{
    const int tid = blockIdx.x * 256 + threadIdx.x;   // N*64 threads exactly
    const int n = tid >> 6;          // 64 double2 per row
    const int c = tid & 63;
    const int k = outIdx[n];
    double2 rv = ((double2*)R64)[tid];
    float2  cv = ((const float2*)cb)[(size_t)k * 64 + c];
    rv.x -= (double)cv.x;
    rv.y -= (double)cv.y;
    ((double2*)R64)[tid] = rv;
    float2 out; out.x = (float)rv.x; out.y = (float)rv.y;
    ((float2*)R32)[tid] = out;
}

// ---------------------------------------------------------------------------
extern "C" void kernel_launch(void* const* d_in, const int* in_sizes, int n_in,
                              void* d_out, int out_size, void* d_ws, size_t ws_size,
                              hipStream_t stream)
{
    const float* emb       = (const float*)d_in[0];   // [B, D, T] fp32
    const float* codebooks = (const float*)d_in[1];   // [Q, K, D] fp32
    int* outIdx = (int*)d_out;                        // [Q, B, T] int32

    // Workspace layout (doubles first for 8B alignment):
    char* ws = (char*)d_ws;
    double* R64      = (double*)ws;                    size_t off = (size_t)N_ * D_ * 8;   // 73.7 MB
    double* normD    = (double*)(ws + off);            off += (size_t)Q_ * K_ * 8;
    float*  R32      = (float*)(ws + off);             off += (size_t)N_ * D_ * 4;         // 36.9 MB
    float*  normF    = (float*)(ws + off);             off += (size_t)Q_ * K_ * 4;
    int*    flagList = (int*)(ws + off);               off += (size_t)N_ * 4;
    int*    counters = (int*)(ws + off);               off += (size_t)Q_ * 4;

    hipMemsetAsync(counters, 0, Q_ * 4, stream);

    dim3 tb(32, 8, 1);
    dim3 tg((T_ + 31) / 32, D_ / 32, B_);
    transpose_kernel<<<tg, tb, 0, stream>>>(emb, R32, R64);
    norms_kernel<<<Q_ * K_, 64, 0, stream>>>(codebooks, normF, normD);

    for (int q = 0; q < Q_; ++q) {
        const float* cb = codebooks + (size_t)q * K_ * D_;
        int* oq = outIdx + (size_t)q * N_;
        layer_fast<<<N_ / 64, 64, 0, stream>>>(R32, cb, normF + (size_t)q * K_,
                                               oq, flagList, counters + q);
        layer_rescore<<<2048, 64, 0, stream>>>(R64, cb, normD + (size_t)q * K_,
                                               flagList, counters + q, oq);
        if (q < Q_ - 1) {
            layer_update<<<(N_ * 64) / 256, 256, 0, stream>>>(R64, R32, cb, oq);
        }
    }
}

// Round 3
// 18735.600 us; speedup vs baseline: 3.1124x; 3.1124x over previous
//
#include <hip/hip_runtime.h>
#include <hip/hip_bf16.h>

// Problem constants: B=32, D=128, T=2250, Q=32, K=1024
#define B_ 32
#define D_ 128
#define T_ 2250
#define Q_ 32
#define K_ 1024
#define N_ (B_ * T_)   // 72000

#define KT 64          // codes per k-tile
#define NTILES (K_ / KT)
#define TAU 0.25f

// ---------------------------------------------------------------------------
// Transpose embeddings [B, D, T] -> R32/R64 [N, D] with n = b*T + t
// ---------------------------------------------------------------------------
__global__ void transpose_kernel(const float* __restrict__ emb,
                                 float* __restrict__ R32,
                                 double* __restrict__ R64)
{
    __shared__ float tile[32][33];
    const int b  = blockIdx.z;
    const int t0 = blockIdx.x * 32;
    const int d0 = blockIdx.y * 32;

    for (int i = threadIdx.y; i < 32; i += 8) {
        int t = t0 + threadIdx.x;
        int d = d0 + i;
        tile[i][threadIdx.x] = (t < T_) ? emb[((size_t)b * D_ + d) * T_ + t] : 0.0f;
    }
    __syncthreads();
    for (int i = threadIdx.y; i < 32; i += 8) {
        int t = t0 + i;
        if (t < T_) {
            float v = tile[threadIdx.x][i];
            size_t o = ((size_t)b * T_ + t) * D_ + d0 + threadIdx.x;
            R32[o] = v;
            R64[o] = (double)v;
        }
    }
}

// ---------------------------------------------------------------------------
// Per-code squared norms: fp32 (fast pass) and fp64 (rescore). One wave/code.
// ---------------------------------------------------------------------------
__global__ __launch_bounds__(64) void norms_kernel(const float* __restrict__ codebooks,
                                                   float* __restrict__ normF,
                                                   double* __restrict__ normD)
{
    const int code = blockIdx.x;            // 0 .. Q*K-1
    const float* e = codebooks + (size_t)code * D_;
    const int lane = threadIdx.x;
    float f0 = e[lane];
    float f1 = e[lane + 64];
    double acc = (double)f0 * (double)f0 + (double)f1 * (double)f1;
    #pragma unroll
    for (int off = 32; off > 0; off >>= 1) acc += __shfl_down(acc, off);
    if (lane == 0) {
        normD[code] = acc;
        normF[code] = (float)acc;
    }
}

// ---------------------------------------------------------------------------
// Fast pass, LDS-tiled register GEMM + fused top-2.
// Block: 256 threads -> 64 points x 1024 codes (16 k-tiles of 64).
// LDS layout (quad-transposed): Aq[dq][p] float4, Bq[dq][k] float4.
// Thread (tx,ty): points p = ty + 16*i, codes k = ktBase + tx + 16*j.
// ---------------------------------------------------------------------------
__global__ __launch_bounds__(256) void layer_fast(
    const float* __restrict__ R32,
    const float* __restrict__ cb,      // [K, D] this layer's codebook
    const float* __restrict__ normF,   // [K]
    int* __restrict__ outIdx,          // [N]
    int* __restrict__ flagList,
    int* __restrict__ flagCount)
{
    __shared__ float lds[16384];            // 64 KB: Aq [0,8192) float4, Bq [8192,16384)
    float4* Aq = (float4*)lds;              // index: dq*64 + p
    float4* Bq = ((float4*)lds) + 2048;     // index: dq*64 + k

    const int tid  = threadIdx.x;
    const int lane = tid & 63;
    const int w    = tid >> 6;              // wave 0..3
    const int ty   = lane & 15;             // point group 0..15
    const int tx   = w * 4 + (lane >> 4);   // code group 0..15 (4 distinct per wave)
    const size_t rowBase = (size_t)blockIdx.x * 64;

    // ---- Stage A (64 rows x 128 dims) quad-transposed ----
    // lane-strided read: f = w*512 + lane*8 + i -> p = f>>5 spans 16 values per
    // instr -> LDS write bank starts 4p%32 -> 2-way (free). Global reads are
    // block-local 32 KB, absorbed by L1/L2.
    {
        const float4* src = (const float4*)(R32 + rowBase * D_);
        #pragma unroll
        for (int i = 0; i < 8; ++i) {
            int f = w * 512 + lane * 8 + i;
            Aq[(f & 31) * 64 + (f >> 5)] = src[f];
        }
    }

    // ---- Prefetch first B tile into registers ----
    float4 pf[8];
    {
        const float4* src = (const float4*)cb;
        #pragma unroll
        for (int i = 0; i < 8; ++i) pf[i] = src[w * 512 + lane * 8 + i];
    }

    float b1[4], b2[4]; int k1[4];
    #pragma unroll
    for (int i = 0; i < 4; ++i) { b1[i] = -3.4e38f; b2[i] = -3.4e38f; k1[i] = 0; }

    for (int kt = 0; kt < NTILES; ++kt) {
        __syncthreads();                    // Bs free (and As ready on kt==0)
        #pragma unroll
        for (int i = 0; i < 8; ++i) {
            int f = w * 512 + lane * 8 + i;
            Bq[(f & 31) * 64 + (f >> 5)] = pf[i];
        }
        if (kt + 1 < NTILES) {              // prefetch next tile (latency hidden by compute)
            const float4* src = (const float4*)(cb + (size_t)(kt + 1) * KT * D_);
            #pragma unroll
            for (int i = 0; i < 8; ++i) pf[i] = src[w * 512 + lane * 8 + i];
        }
        float nf[4];
        #pragma unroll
        for (int j = 0; j < 4; ++j) nf[j] = normF[kt * KT + tx + 16 * j];
        __syncthreads();                    // Bs ready

        float acc[4][4];
        #pragma unroll
        for (int i = 0; i < 4; ++i)
            #pragma unroll
            for (int j = 0; j < 4; ++j) acc[i][j] = 0.f;

        // Inner loop: per dq, 8 ds_read_b128 (immediate offsets) + 64 FMA.
        #pragma unroll 8
        for (int dq = 0; dq < 32; ++dq) {
            float4 a[4], b[4];
            #pragma unroll
            for (int i = 0; i < 4; ++i) a[i] = Aq[dq * 64 + ty + 16 * i];
            #pragma unroll
            for (int j = 0; j < 4; ++j) b[j] = Bq[dq * 64 + tx + 16 * j];
            #pragma unroll
            for (int i = 0; i < 4; ++i)
                #pragma unroll
                for (int j = 0; j < 4; ++j) {
                    acc[i][j] = fmaf(a[i].x, b[j].x, acc[i][j]);
                    acc[i][j] = fmaf(a[i].y, b[j].y, acc[i][j]);
                    acc[i][j] = fmaf(a[i].z, b[j].z, acc[i][j]);
                    acc[i][j] = fmaf(a[i].w, b[j].w, acc[i][j]);
                }
        }

        // Finalize scores for this tile; update running top-2 (j ascending = k ascending)
        #pragma unroll
        for (int j = 0; j < 4; ++j) {
            int k = kt * KT + tx + 16 * j;
            #pragma unroll
            for (int i = 0; i < 4; ++i) {
                float s = fmaf(2.f, acc[i][j], -nf[j]);
                if (s > b1[i])      { b2[i] = b1[i]; b1[i] = s; k1[i] = k; }
                else if (s > b2[i]) { b2[i] = s; }
            }
        }
    }

    // ---- Cross-thread merge over tx via LDS (reuse tile memory) ----
    __syncthreads();
    float* s1 = lds;                 // [16][64]
    float* s2 = lds + 1024;
    int*   sk = (int*)(lds + 2048);
    #pragma unroll
    for (int i = 0; i < 4; ++i) {
        int p = ty + 16 * i;
        s1[tx * 64 + p] = b1[i];
        s2[tx * 64 + p] = b2[i];
        sk[tx * 64 + p] = k1[i];
    }
    __syncthreads();
    if (tid < 64) {
        const int p = tid;
        float B1 = -3.4e38f, B2 = -3.4e38f; int K1 = 0;
        for (int t = 0; t < 16; ++t) {
            float v1 = s1[t * 64 + p];
            float v2 = s2[t * 64 + p];
            int   kk = sk[t * 64 + p];
            if (v1 > B1) { B2 = fmaxf(B1, v2); B1 = v1; K1 = kk; }
            else         { B2 = fmaxf(B2, v1); }
        }
        const int n = (int)rowBase + p;
        outIdx[n] = K1;
        if (B1 - B2 < TAU) {            // near-tie (or exact tie): fp64 rescore decides
            int pos = atomicAdd(flagCount, 1);
            flagList[pos] = n;
        }
    }
}

// ---------------------------------------------------------------------------
// fp64 rescore of flagged points against the fp64 residual. One wave/point.
// ---------------------------------------------------------------------------
__global__ __launch_bounds__(64) void layer_rescore(
    const double* __restrict__ R64,
    const float* __restrict__ cb,
    const double* __restrict__ normD,
    const int* __restrict__ flagList,
    const int* __restrict__ flagCount,
    int* __restrict__ outIdx)
{
    const int cnt = *flagCount;
    const int lane = threadIdx.x;
    for (int i = blockIdx.x; i < cnt; i += gridDim.x) {
        const int n = flagList[i];
        const double* __restrict__ r = R64 + (size_t)n * D_;
        double best = -1.0e300;
        int bi = K_;
        for (int k = lane; k < K_; k += 64) {
            const float* __restrict__ c = cb + (size_t)k * D_;
            double a0 = 0.0, a1 = 0.0;
            #pragma unroll 8
            for (int j = 0; j < D_; j += 2) {
                a0 = fma(r[j],     (double)c[j],     a0);
                a1 = fma(r[j + 1], (double)c[j + 1], a1);
            }
            double s = 2.0 * (a0 + a1) - normD[k];
            if (s > best) { best = s; bi = k; }   // strict > : lowest k in lane wins
        }
        #pragma unroll
        for (int off = 32; off > 0; off >>= 1) {
            double ob = __shfl_down(best, off);
            int    oi = __shfl_down(bi, off);
            if (ob > best || (ob == best && oi < bi)) { best = ob; bi = oi; }
        }
        if (lane == 0) outIdx[n] = bi;
    }
}

// ---------------------------------------------------------------------------
// Residual update in fp64: R64[n] -= cb[idx[n]]; R32 = (float)R64.
// ---------------------------------------------------------------------------
__global__ void layer_update(double* __restrict__ R64,
                             float* __restrict__ R32,
                             const float* __restrict__ cb,
                             const int* __restrict__ outIdx)
{
    const int tid = blockIdx.x * 256 + threadIdx.x;   // N*64 threads exactly
    const int n = tid >> 6;          // 64 double2 per row
    const int c = tid & 63;
    const int k = outIdx[n];
    double2 rv = ((double2*)R64)[tid];
    float2  cv = ((const float2*)cb)[(size_t)k * 64 + c];
    rv.x -= (double)cv.x;
    rv.y -= (double)cv.y;
    ((double2*)R64)[tid] = rv;
    float2 out; out.x = (float)rv.x; out.y = (float)rv.y;
    ((float2*)R32)[tid] = out;
}

// ---------------------------------------------------------------------------
extern "C" void kernel_launch(void* const* d_in, const int* in_sizes, int n_in,
                              void* d_out, int out_size, void* d_ws, size_t ws_size,
                              hipStream_t stream)
{
    const float* emb       = (const float*)d_in[0];   // [B, D, T] fp32
    const float* codebooks = (const float*)d_in[1];   // [Q, K, D] fp32
    int* outIdx = (int*)d_out;                        // [Q, B, T] int32

    // Workspace layout (doubles first for 8B alignment):
    char* ws = (char*)d_ws;
    double* R64      = (double*)ws;                    size_t off = (size_t)N_ * D_ * 8;
    double* normD    = (double*)(ws + off);            off += (size_t)Q_ * K_ * 8;
    float*  R32      = (float*)(ws + off);             off += (size_t)N_ * D_ * 4;
    float*  normF    = (float*)(ws + off);             off += (size_t)Q_ * K_ * 4;
    int*    flagList = (int*)(ws + off);               off += (size_t)N_ * 4;
    int*    counters = (int*)(ws + off);               off += (size_t)Q_ * 4;

    hipMemsetAsync(counters, 0, Q_ * 4, stream);

    dim3 tb(32, 8, 1);
    dim3 tg((T_ + 31) / 32, D_ / 32, B_);
    transpose_kernel<<<tg, tb, 0, stream>>>(emb, R32, R64);
    norms_kernel<<<Q_ * K_, 64, 0, stream>>>(codebooks, normF, normD);

    for (int q = 0; q < Q_; ++q) {
        const float* cb = codebooks + (size_t)q * K_ * D_;
        int* oq = outIdx + (size_t)q * N_;
        layer_fast<<<N_ / 64, 256, 0, stream>>>(R32, cb, normF + (size_t)q * K_,
                                                oq, flagList, counters + q);
        layer_rescore<<<2048, 64, 0, stream>>>(R64, cb, normD + (size_t)q * K_,
                                               flagList, counters + q, oq);
        if (q < Q_ - 1) {
            layer_update<<<(N_ * 64) / 256, 256, 0, stream>>>(R64, R32, cb, oq);
        }
    }
}

// Round 4
// 9848.689 us; speedup vs baseline: 5.9208x; 1.9023x over previous
//
#include <hip/hip_runtime.h>
#include <hip/hip_bf16.h>

// Problem constants: B=32, D=128, T=2250, Q=32, K=1024
#define B_ 32
#define D_ 128
#define T_ 2250
#define Q_ 32
#define K_ 1024
#define N_ (B_ * T_)      // 72000
#define NPAD 72064        // 563 * 128 (points padded so 128-tiles need no guards)
#define TAU 0.25f

typedef short bf16x8 __attribute__((ext_vector_type(8)));
typedef float f32x4 __attribute__((ext_vector_type(4)));

__device__ __forceinline__ void load_lds16(const void* g, void* l) {
    __builtin_amdgcn_global_load_lds(
        (const __attribute__((address_space(1))) void*)g,
        (__attribute__((address_space(3))) void*)l, 16, 0, 0);
}

__device__ __forceinline__ void split_bf16(float x, unsigned short& hb, unsigned short& lb) {
    __hip_bfloat16 h = __float2bfloat16(x);
    float hf = __bfloat162float(h);
    __hip_bfloat16 l = __float2bfloat16(x - hf);
    hb = *(unsigned short*)&h;
    lb = *(unsigned short*)&l;
}

// ---------------------------------------------------------------------------
// Transpose embeddings [B, D, T] -> R64 [N,128] fp64 + Rhi/Rlo [NPAD,128] bf16
// ---------------------------------------------------------------------------
__global__ void transpose_kernel(const float* __restrict__ emb,
                                 double* __restrict__ R64,
                                 unsigned short* __restrict__ Rhi,
                                 unsigned short* __restrict__ Rlo)
{
    __shared__ float tile[32][33];
    const int b  = blockIdx.z;
    const int t0 = blockIdx.x * 32;
    const int d0 = blockIdx.y * 32;

    for (int i = threadIdx.y; i < 32; i += 8) {
        int t = t0 + threadIdx.x;
        int d = d0 + i;
        tile[i][threadIdx.x] = (t < T_) ? emb[((size_t)b * D_ + d) * T_ + t] : 0.0f;
    }
    __syncthreads();
    for (int i = threadIdx.y; i < 32; i += 8) {
        int t = t0 + i;
        if (t < T_) {
            float v = tile[threadIdx.x][i];
            size_t o = ((size_t)b * T_ + t) * D_ + d0 + threadIdx.x;
            R64[o] = (double)v;
            unsigned short hb, lb;
            split_bf16(v, hb, lb);
            Rhi[o] = hb;
            Rlo[o] = lb;
        }
    }
}

// ---------------------------------------------------------------------------
// Codebook hi/lo split (once): [Q*K*D] fp32 -> bf16 hi + bf16 lo
// ---------------------------------------------------------------------------
__global__ void split_cb_kernel(const float* __restrict__ cbs,
                                unsigned short* __restrict__ Ehi,
                                unsigned short* __restrict__ Elo)
{
    int i = blockIdx.x * 256 + threadIdx.x;   // Q*K*D threads exactly
    float x = cbs[i];
    unsigned short hb, lb;
    split_bf16(x, hb, lb);
    Ehi[i] = hb;
    Elo[i] = lb;
}

// ---------------------------------------------------------------------------
// Per-code squared norms: fp32 (fast pass) and fp64 (rescore). One wave/code.
// ---------------------------------------------------------------------------
__global__ __launch_bounds__(64) void norms_kernel(const float* __restrict__ codebooks,
                                                   float* __restrict__ normF,
                                                   double* __restrict__ normD)
{
    const int code = blockIdx.x;            // 0 .. Q*K-1
    const float* e = codebooks + (size_t)code * D_;
    const int lane = threadIdx.x;
    float f0 = e[lane];
    float f1 = e[lane + 64];
    double acc = (double)f0 * (double)f0 + (double)f1 * (double)f1;
    #pragma unroll
    for (int off = 32; off > 0; off >>= 1) acc += __shfl_down(acc, off);
    if (lane == 0) {
        normD[code] = acc;
        normF[code] = (float)acc;
    }
}

// ---------------------------------------------------------------------------
// MFMA fast pass: block = 128 points x 128 codes, 256 threads (2x2 waves,
// each wave 64x64 via 4x4 frags of 16x16x32 bf16). K-loop: 12 steps of 32
// (3 split passes x D=128). Emits per-point top-2 partial for this code
// stripe. m97-style staging: global_load_lds width 16, 2 barriers/kstep.
// ---------------------------------------------------------------------------
__global__ __launch_bounds__(256) void layer_fast(
    const unsigned short* __restrict__ Rhi,   // [NPAD,128]
    const unsigned short* __restrict__ Rlo,
    const unsigned short* __restrict__ Ehi,   // [K,128] (layer offset applied)
    const unsigned short* __restrict__ Elo,
    const float* __restrict__ normF,          // [K] (layer offset applied)
    float* __restrict__ pb1, float* __restrict__ pb2, int* __restrict__ pk1)  // [8][NPAD]
{
    __shared__ __align__(16) char lds[128 * 133 * 4];   // 68 KB (tiles then scores)
    char* As = lds;            // 128 rows x 64 B (32 bf16)
    char* Bs = lds + 8192;     // 128 codes x 64 B

    const int tid  = threadIdx.x;
    const int lane = tid & 63;
    const int w    = tid >> 6;
    const int wr   = w >> 1;            // wave point-row (0..1)
    const int wc   = w & 1;             // wave code-col (0..1)
    const int l15  = lane & 15;
    const int quad = lane >> 4;
    const int mBase = blockIdx.x * 128; // 0..562 -> up to 71936
    const int nBase = blockIdx.y * 128; // code stripe

    f32x4 acc[4][4];
    #pragma unroll
    for (int i = 0; i < 4; ++i)
        #pragma unroll
        for (int j = 0; j < 4; ++j) acc[i][j] = (f32x4){0.f, 0.f, 0.f, 0.f};

    // fragment LDS byte offsets (row stride 64 B)
    const int aOff = (wr * 64 + l15) * 64 + quad * 16;
    const int bOff = 8192 + (wc * 64 + l15) * 64 + quad * 16;

    // staging slots: 512 x 16 B per tile; this thread's two slots
    const int slot0 = w * 128 + lane;         // w*2 iters of 64 ... slots [w*128, w*128+64)
    const int slot1 = slot0 + 64;

    for (int s = 0; s < 12; ++s) {
        const int p  = s >> 2;                 // split pass 0..2
        const int kk = (s & 3) * 64;           // byte offset of 32-elem k-chunk
        const char* Ab = (const char*)((p < 2) ? Rhi : Rlo) + (size_t)mBase * 256 + kk;
        const char* Bb = (const char*)((p != 1) ? Ehi : Elo) + (size_t)nBase * 256 + kk;

        __syncthreads();   // previous tile fully consumed
        {
            int r0 = slot0 >> 2, g0 = (slot0 & 3) * 16;
            int r1 = slot1 >> 2, g1 = (slot1 & 3) * 16;
            load_lds16(Ab + (size_t)r0 * 256 + g0, As + slot0 * 16);
            load_lds16(Ab + (size_t)r1 * 256 + g1, As + slot1 * 16);
            load_lds16(Bb + (size_t)r0 * 256 + g0, Bs + slot0 * 16);
            load_lds16(Bb + (size_t)r1 * 256 + g1, Bs + slot1 * 16);
        }
        __syncthreads();   // staging complete (vmcnt drained before barrier)

        bf16x8 af[4], bfr[4];
        #pragma unroll
        for (int i = 0; i < 4; ++i) af[i]  = *(const bf16x8*)(lds + aOff + i * 1024);
        #pragma unroll
        for (int j = 0; j < 4; ++j) bfr[j] = *(const bf16x8*)(lds + bOff + j * 1024);
        #pragma unroll
        for (int i = 0; i < 4; ++i)
            #pragma unroll
            for (int j = 0; j < 4; ++j)
                acc[i][j] = __builtin_amdgcn_mfma_f32_16x16x32_bf16(af[i], bfr[j], acc[i][j], 0, 0, 0);
    }

    __syncthreads();       // done with tiles; reuse LDS for scores [128][133]
    float* sc = (float*)lds;
    #pragma unroll
    for (int j = 0; j < 4; ++j) {
        const int cl = wc * 64 + j * 16 + l15;
        const float nf = normF[nBase + cl];
        #pragma unroll
        for (int i = 0; i < 4; ++i) {
            #pragma unroll
            for (int r = 0; r < 4; ++r) {
                int ml = wr * 64 + i * 16 + quad * 4 + r;
                sc[ml * 133 + cl] = fmaf(2.0f, acc[i][j][r], -nf);
            }
        }
    }
    __syncthreads();

    // per-point scan of 128 local codes, ascending (first-index tie-break)
    if (tid < 128) {
        float B1 = -3.4e38f, B2 = -3.4e38f;
        int K1 = 0;
        const float* row = sc + tid * 133;
        for (int c = 0; c < 128; ++c) {
            float v = row[c];
            if (v > B1)      { B2 = B1; B1 = v; K1 = c; }
            else if (v > B2) { B2 = v; }
        }
        const int n = mBase + tid;
        const int cb = blockIdx.y;
        pb1[cb * NPAD + n] = B1;
        pb2[cb * NPAD + n] = B2;
        pk1[cb * NPAD + n] = nBase + K1;
    }
}

// ---------------------------------------------------------------------------
// Merge 8 code-stripe partials per point (ascending cb -> first-index wins),
// write index, flag near-ties for fp64 rescore.
// ---------------------------------------------------------------------------
__global__ void reduce_kernel(const float* __restrict__ pb1,
                              const float* __restrict__ pb2,
                              const int* __restrict__ pk1,
                              int* __restrict__ outIdx,
                              int* __restrict__ flagList,
                              int* __restrict__ flagCount)
{
    const int n = blockIdx.x * 256 + threadIdx.x;
    if (n >= N_) return;
    float B1 = -3.4e38f, B2 = -3.4e38f;
    int K1 = 0;
    #pragma unroll
    for (int cb = 0; cb < 8; ++cb) {
        float b1 = pb1[cb * NPAD + n];
        float b2 = pb2[cb * NPAD + n];
        int   k1 = pk1[cb * NPAD + n];
        if (b1 > B1) { B2 = fmaxf(B1, b2); B1 = b1; K1 = k1; }
        else         { B2 = fmaxf(B2, b1); }
    }
    outIdx[n] = K1;
    if (B1 - B2 < TAU) {
        int pos = atomicAdd(flagCount, 1);
        flagList[pos] = n;
    }
}

// ---------------------------------------------------------------------------
// fp64 rescore of flagged points against the fp64 residual. One wave/point.
// ---------------------------------------------------------------------------
__global__ __launch_bounds__(64) void layer_rescore(
    const double* __restrict__ R64,
    const float* __restrict__ cb,
    const double* __restrict__ normD,
    const int* __restrict__ flagList,
    const int* __restrict__ flagCount,
    int* __restrict__ outIdx)
{
    const int cnt = *flagCount;
    const int lane = threadIdx.x;
    for (int i = blockIdx.x; i < cnt; i += gridDim.x) {
        const int n = flagList[i];
        const double* __restrict__ r = R64 + (size_t)n * D_;
        double best = -1.0e300;
        int bi = K_;
        for (int k = lane; k < K_; k += 64) {
            const float* __restrict__ c = cb + (size_t)k * D_;
            double a0 = 0.0, a1 = 0.0;
            #pragma unroll 8
            for (int j = 0; j < D_; j += 2) {
                a0 = fma(r[j],     (double)c[j],     a0);
                a1 = fma(r[j + 1], (double)c[j + 1], a1);
            }
            double s = 2.0 * (a0 + a1) - normD[k];
            if (s > best) { best = s; bi = k; }   // strict > : lowest k in lane wins
        }
        #pragma unroll
        for (int off = 32; off > 0; off >>= 1) {
            double ob = __shfl_down(best, off);
            int    oi = __shfl_down(bi, off);
            if (ob > best || (ob == best && oi < bi)) { best = ob; bi = oi; }
        }
        if (lane == 0) outIdx[n] = bi;
    }
}

// ---------------------------------------------------------------------------
// Residual update in fp64: R64 -= cb[idx]; refresh bf16 hi/lo shadows.
// One double2 (2 dims) per thread; N*64 threads.
// ---------------------------------------------------------------------------
__global__ void layer_update(double* __restrict__ R64,
                             unsigned short* __restrict__ Rhi,
                             unsigned short* __restrict__ Rlo,
                             const float* __restrict__ cb,
                             const int* __restrict__ outIdx)
{
    const int tid = blockIdx.x * 256 + threadIdx.x;   // N*64 threads exactly
    const int n = tid >> 6;
    const int c = tid & 63;
    const int k = outIdx[n];
    double2 rv = ((double2*)R64)[tid];
    float2  cv = ((const float2*)cb)[(size_t)k * 64 + c];
    rv.x -= (double)cv.x;
    rv.y -= (double)cv.y;
    ((double2*)R64)[tid] = rv;
    unsigned short hx, lx, hy, ly;
    split_bf16((float)rv.x, hx, lx);
    split_bf16((float)rv.y, hy, ly);
    ((uint*)Rhi)[tid] = (uint)hx | ((uint)hy << 16);
    ((uint*)Rlo)[tid] = (uint)lx | ((uint)ly << 16);
}

// ---------------------------------------------------------------------------
extern "C" void kernel_launch(void* const* d_in, const int* in_sizes, int n_in,
                              void* d_out, int out_size, void* d_ws, size_t ws_size,
                              hipStream_t stream)
{
    const float* emb       = (const float*)d_in[0];   // [B, D, T] fp32
    const float* codebooks = (const float*)d_in[1];   // [Q, K, D] fp32
    int* outIdx = (int*)d_out;                        // [Q, B, T] int32

    char* ws = (char*)d_ws;
    double* R64  = (double*)ws;                        size_t off = (size_t)N_ * D_ * 8;
    double* normD = (double*)(ws + off);               off += (size_t)Q_ * K_ * 8;
    unsigned short* Rhi = (unsigned short*)(ws + off); off += (size_t)NPAD * D_ * 2;
    unsigned short* Rlo = (unsigned short*)(ws + off); off += (size_t)NPAD * D_ * 2;
    unsigned short* Ehi = (unsigned short*)(ws + off); off += (size_t)Q_ * K_ * D_ * 2;
    unsigned short* Elo = (unsigned short*)(ws + off); off += (size_t)Q_ * K_ * D_ * 2;
    float* normF    = (float*)(ws + off);              off += (size_t)Q_ * K_ * 4;
    float* pb1      = (float*)(ws + off);              off += (size_t)8 * NPAD * 4;
    float* pb2      = (float*)(ws + off);              off += (size_t)8 * NPAD * 4;
    int*   pk1      = (int*)(ws + off);                off += (size_t)8 * NPAD * 4;
    int*   flagList = (int*)(ws + off);                off += (size_t)N_ * 4;
    int*   counters = (int*)(ws + off);                off += (size_t)Q_ * 4;

    hipMemsetAsync(counters, 0, Q_ * 4, stream);
    // zero the pad rows (72000..72063) of the bf16 shadows so staging is guard-free
    hipMemsetAsync((char*)Rhi + (size_t)N_ * 256, 0, (size_t)(NPAD - N_) * 256, stream);
    hipMemsetAsync((char*)Rlo + (size_t)N_ * 256, 0, (size_t)(NPAD - N_) * 256, stream);

    dim3 tb(32, 8, 1);
    dim3 tg((T_ + 31) / 32, D_ / 32, B_);
    transpose_kernel<<<tg, tb, 0, stream>>>(emb, R64, Rhi, Rlo);
    split_cb_kernel<<<(Q_ * K_ * D_) / 256, 256, 0, stream>>>(codebooks, Ehi, Elo);
    norms_kernel<<<Q_ * K_, 64, 0, stream>>>(codebooks, normF, normD);

    for (int q = 0; q < Q_; ++q) {
        const float* cb = codebooks + (size_t)q * K_ * D_;
        int* oq = outIdx + (size_t)q * N_;
        layer_fast<<<dim3(563, 8), 256, 0, stream>>>(
            Rhi, Rlo, Ehi + (size_t)q * K_ * D_, Elo + (size_t)q * K_ * D_,
            normF + (size_t)q * K_, pb1, pb2, pk1);
        reduce_kernel<<<(N_ + 255) / 256, 256, 0, stream>>>(pb1, pb2, pk1, oq,
                                                            flagList, counters + q);
        layer_rescore<<<2048, 64, 0, stream>>>(R64, cb, normD + (size_t)q * K_,
                                               flagList, counters + q, oq);
        if (q < Q_ - 1) {
            layer_update<<<(N_ * 64) / 256, 256, 0, stream>>>(R64, Rhi, Rlo, cb, oq);
        }
    }
}